// Round 1
// baseline (225.897 us; speedup 1.0000x reference)
//
#include <hip/hip_runtime.h>
#include <math.h>

// MoE top-2 router. Round 4: fully fused. convert_w (W fp32 -> bf16 hi/lo)
// then ONE kernel: 64-token blocks, full K=2048, double-buffered
// global_load_lds staging (same XOR-swizzle as round 3), 3-MFMA bf16 hi/lo
// GEMM, then in-register softmax + top-2 + all outputs via 16-lane shuffle
// trees. No partial-logits round trip, no reduce kernel.
//
// x: [16384, 2048] fp32, W: [64, 2048] fp32.
// outputs (concat, fp32): mask [T,64], idx-as-float [T,2],
//                         router_probs [T,64], probs [T,64]

#define D_DIM 2048
#define E_DIM 64

typedef __bf16 bf16x8 __attribute__((ext_vector_type(8)));
typedef unsigned short us8 __attribute__((ext_vector_type(8)));
typedef float f32x4 __attribute__((ext_vector_type(4)));

static __device__ __forceinline__ unsigned short f2bf(float f) {
    unsigned int u = __float_as_uint(f);
    u += 0x7fffu + ((u >> 16) & 1u);   // RNE
    return (unsigned short)(u >> 16);
}
static __device__ __forceinline__ float bf2f(unsigned short h) {
    return __uint_as_float(((unsigned int)h) << 16);
}
static __device__ __forceinline__ void split4(const float4 v, ushort4* h, ushort4* l) {
    h->x = f2bf(v.x); l->x = f2bf(v.x - bf2f(h->x));
    h->y = f2bf(v.y); l->y = f2bf(v.y - bf2f(h->y));
    h->z = f2bf(v.z); l->z = f2bf(v.z - bf2f(h->z));
    h->w = f2bf(v.w); l->w = f2bf(v.w - bf2f(h->w));
}

static __device__ __forceinline__ void gld_lds16(const void* g, void* l) {
    __builtin_amdgcn_global_load_lds(
        (const __attribute__((address_space(1))) unsigned int*)g,
        (__attribute__((address_space(3))) unsigned int*)l,
        16, 0, 0);
}

// ---- pre-convert W (64x2048 fp32) -> bf16 hi/lo, linear layout ----
__global__ __launch_bounds__(256, 1) void convert_w(
    const float4* __restrict__ W4, unsigned short* __restrict__ WH,
    unsigned short* __restrict__ WL)
{
    int i = blockIdx.x * 256 + threadIdx.x;   // float4 index
    float4 v = W4[i];
    ushort4 h, l;
    split4(v, &h, &l);
    *(ushort4*)&WH[i * 4] = h;
    *(ushort4*)&WL[i * 4] = l;
}

// ---- fused GEMM + softmax + top-2 + outputs ----
// block = 64 tokens x all 64 experts x K=2048; 256 threads (4 waves);
// wave wv owns tokens wv*16..wv*16+15 with the FULL 64-expert logit row.
__global__ __launch_bounds__(256, 1) void router_fused(
    const float* __restrict__ x,
    const unsigned short* __restrict__ WHg, const unsigned short* __restrict__ WLg,
    float* __restrict__ mask_out, float* __restrict__ idx_out,
    float* __restrict__ rp_out, float* __restrict__ probs_out)
{
    // 16B-slot-swizzled LDS tiles, double-buffered (64 KB total)
    __shared__ __align__(16) float          XF [2][64 * 64];  // 2x16 KB fp32 x
    __shared__ __align__(16) unsigned short WHs[2][64 * 64];  // 2x 8 KB
    __shared__ __align__(16) unsigned short WLs[2][64 * 64];  // 2x 8 KB

    const int tid  = threadIdx.x;
    const int lane = tid & 63;
    const int wv   = tid >> 6;
    const int quad = lane >> 4;
    const int l16  = lane & 15;

    const int t0  = blockIdx.x << 6;
    const int NCH = D_DIM >> 6;               // 32 chunks of 64 k

    f32x4 acc[4];
    #pragma unroll
    for (int n = 0; n < 4; ++n) { f32x4 z = {0.f, 0.f, 0.f, 0.f}; acc[n] = z; }

    // staging-lane constants (identical to round 3)
    const int srow = wv * 4 + (lane >> 4);    // + 16*i  -> x row
    const int scg  = lane & 15;               // x float4 col before swizzle
    const int we   = wv * 8 + (lane >> 3);    // + 32*i2 -> W expert row
    const int wo   = lane & 7;                // W k-octet before swizzle

    // ---- prologue: stage chunk 0 into buffer 0 ----
    {
        #pragma unroll
        for (int i = 0; i < 4; ++i) {
            int row = i * 16 + srow;
            int cg  = scg ^ (row & 15);
            gld_lds16(x + (size_t)(t0 + row) * D_DIM + cg * 4,
                      &XF[0][(i * 256 + wv * 64) * 4]);
        }
        #pragma unroll
        for (int i2 = 0; i2 < 2; ++i2) {
            int e  = i2 * 32 + we;
            int og = wo ^ (e & 7);
            gld_lds16(WHg + (size_t)e * D_DIM + og * 8,
                      &WHs[0][(i2 * 256 + wv * 64) * 8]);
            gld_lds16(WLg + (size_t)e * D_DIM + og * 8,
                      &WLs[0][(i2 * 256 + wv * 64) * 8]);
        }
    }
    __syncthreads();   // drains vmcnt(0): chunk 0 resident

    int buf = 0;
    for (int ch = 0; ch < NCH; ++ch) {
        // ---- issue next-chunk stage into buf^1 BEFORE computing ----
        if (ch + 1 < NCH) {
            const int kc = (ch + 1) << 6;
            const int nb = buf ^ 1;
            #pragma unroll
            for (int i = 0; i < 4; ++i) {
                int row = i * 16 + srow;
                int cg  = scg ^ (row & 15);
                gld_lds16(x + (size_t)(t0 + row) * D_DIM + kc + cg * 4,
                          &XF[nb][(i * 256 + wv * 64) * 4]);
            }
            #pragma unroll
            for (int i2 = 0; i2 < 2; ++i2) {
                int e  = i2 * 32 + we;
                int og = wo ^ (e & 7);
                gld_lds16(WHg + (size_t)e * D_DIM + kc + og * 8,
                          &WHs[nb][(i2 * 256 + wv * 64) * 8]);
                gld_lds16(WLg + (size_t)e * D_DIM + kc + og * 8,
                          &WLs[nb][(i2 * 256 + wv * 64) * 8]);
            }
        }

        // ---- compute current buffer: 2 k-steps of 32 ----
        #pragma unroll
        for (int ks = 0; ks < 2; ++ks) {
            const int tr = wv * 16 + l16;                 // token row
            const int c0 = ks * 8 + quad * 2;             // float4 col of k-window
            float4 xa = *(const float4*)&XF[buf][(tr * 16 + ( c0      ^ (tr & 15))) * 4];
            float4 xb = *(const float4*)&XF[buf][(tr * 16 + ((c0 + 1) ^ (tr & 15))) * 4];
            ushort4 h0, l0, h1, l1;
            split4(xa, &h0, &l0);
            split4(xb, &h1, &l1);
            union { us8 u; bf16x8 b; } ua, ul;
            ua.u = (us8){h0.x, h0.y, h0.z, h0.w, h1.x, h1.y, h1.z, h1.w};
            ul.u = (us8){l0.x, l0.y, l0.z, l0.w, l1.x, l1.y, l1.z, l1.w};

            #pragma unroll
            for (int n = 0; n < 4; ++n) {
                int e = n * 16 + l16;
                int o = ks * 4 + quad;
                int s = e * 8 + (o ^ (e & 7));
                bf16x8 bh = *(const bf16x8*)&WHs[buf][s * 8];
                bf16x8 bl = *(const bf16x8*)&WLs[buf][s * 8];
                acc[n] = __builtin_amdgcn_mfma_f32_16x16x32_bf16(ua.b, bh, acc[n], 0, 0, 0);
                acc[n] = __builtin_amdgcn_mfma_f32_16x16x32_bf16(ul.b, bh, acc[n], 0, 0, 0);
                acc[n] = __builtin_amdgcn_mfma_f32_16x16x32_bf16(ua.b, bl, acc[n], 0, 0, 0);
            }
        }
        __syncthreads();   // all waves done reading buf; next stage resident
        buf ^= 1;
    }

    // ---- epilogue: softmax + top-2 entirely in-register ----
    // acc[n][r] = logit(token = wv*16 + quad*4 + r, expert = n*16 + l16).
    // Each token's 64 experts live in its quad's 16 lanes x 4 n-slots:
    // reduce with 16-lane xor-shuffle trees (off=1,2,4,8 stays in-quad).
    #pragma unroll
    for (int r = 0; r < 4; ++r) {
        const int t = t0 + wv * 16 + quad * 4 + r;
        const float v0 = acc[0][r], v1 = acc[1][r], v2 = acc[2][r], v3 = acc[3][r];

        // argmax, lower-index tie-break (matches jax.lax.top_k):
        // local scan n ascending (strict > keeps lowest expert), then tree.
        float bv = v0; int bi = l16;
        if (v1 > bv) { bv = v1; bi = 16 + l16; }
        if (v2 > bv) { bv = v2; bi = 32 + l16; }
        if (v3 > bv) { bv = v3; bi = 48 + l16; }
        #pragma unroll
        for (int off = 1; off < 16; off <<= 1) {
            float ov = __shfl_xor(bv, off);
            int   oi = __shfl_xor(bi, off);
            bool take = (ov > bv) || (ov == bv && oi < bi);
            bv = take ? ov : bv;
            bi = take ? oi : bi;
        }
        const float m = bv; const int i1 = bi;

        const float p0 = __expf(v0 - m), p1 = __expf(v1 - m);
        const float p2 = __expf(v2 - m), p3 = __expf(v3 - m);
        float s = p0 + p1 + p2 + p3;
        #pragma unroll
        for (int off = 1; off < 16; off <<= 1) s += __shfl_xor(s, off);

        // second argmax excluding i1
        const float w0 = (i1 == l16)      ? -INFINITY : v0;
        const float w1 = (i1 == 16 + l16) ? -INFINITY : v1;
        const float w2 = (i1 == 32 + l16) ? -INFINITY : v2;
        const float w3 = (i1 == 48 + l16) ? -INFINITY : v3;
        float cv = w0; int ci = l16;
        if (w1 > cv) { cv = w1; ci = 16 + l16; }
        if (w2 > cv) { cv = w2; ci = 32 + l16; }
        if (w3 > cv) { cv = w3; ci = 48 + l16; }
        #pragma unroll
        for (int off = 1; off < 16; off <<= 1) {
            float ov = __shfl_xor(cv, off);
            int   oi = __shfl_xor(ci, off);
            bool take = (ov > cv) || (ov == cv && oi < ci);
            cv = take ? ov : cv;
            ci = take ? oi : ci;
        }
        const int i2 = ci;

        const float inv_s = 1.f / s;
        const float q0 = p0 * inv_s, q1 = p1 * inv_s;
        const float q2 = p2 * inv_s, q3 = p3 * inv_s;
        const bool m0 = (l16 == i1)      || (l16 == i2);
        const bool m1 = (16 + l16 == i1) || (16 + l16 == i2);
        const bool m2 = (32 + l16 == i1) || (32 + l16 == i2);
        const bool m3 = (48 + l16 == i1) || (48 + l16 == i2);

        float pd = (m0 ? q0 : 0.f) + (m1 ? q1 : 0.f)
                 + (m2 ? q2 : 0.f) + (m3 ? q3 : 0.f);
        #pragma unroll
        for (int off = 1; off < 16; off <<= 1) pd += __shfl_xor(pd, off);
        const float ipd = 1.f / pd;

        const size_t base = (size_t)t * 64 + l16;
        probs_out[base]      = q0;
        probs_out[base + 16] = q1;
        probs_out[base + 32] = q2;
        probs_out[base + 48] = q3;
        mask_out[base]      = m0 ? 1.f : 0.f;
        mask_out[base + 16] = m1 ? 1.f : 0.f;
        mask_out[base + 32] = m2 ? 1.f : 0.f;
        mask_out[base + 48] = m3 ? 1.f : 0.f;
        rp_out[base]      = m0 ? q0 * ipd : 0.f;
        rp_out[base + 16] = m1 ? q1 * ipd : 0.f;
        rp_out[base + 32] = m2 ? q2 * ipd : 0.f;
        rp_out[base + 48] = m3 ? q3 * ipd : 0.f;
        if (l16 == 0) {
            idx_out[(size_t)t * 2]     = (float)i1;
            idx_out[(size_t)t * 2 + 1] = (float)i2;
        }
    }
}

extern "C" void kernel_launch(void* const* d_in, const int* in_sizes, int n_in,
                              void* d_out, int out_size, void* d_ws, size_t ws_size,
                              hipStream_t stream) {
    const float* x = (const float*)d_in[0];
    const float* W = (const float*)d_in[1];
    float* out = (float*)d_out;

    const int T  = in_sizes[0] / D_DIM;     // 16384 tokens
    const int WN = in_sizes[1];             // 131072 elements

    unsigned short* WH = (unsigned short*)d_ws;
    unsigned short* WL = WH + WN;           // total ws use: 512 KB

    float* mask_out  = out;
    float* idx_out   = out + (size_t)T * E_DIM;
    float* rp_out    = idx_out + (size_t)T * 2;
    float* probs_out = rp_out + (size_t)T * E_DIM;

    convert_w<<<dim3(WN / 1024), dim3(256), 0, stream>>>((const float4*)W, WH, WL);
    router_fused<<<dim3(T / 64), dim3(256), 0, stream>>>(
        x, WH, WL, mask_out, idx_out, rp_out, probs_out);
}